// Round 1
// baseline (756.038 us; speedup 1.0000x reference)
//
#include <hip/hip_runtime.h>

typedef __bf16 bf16x8 __attribute__((ext_vector_type(8)));
typedef float f32x4 __attribute__((ext_vector_type(4)));

#define B_SZ 4
#define S_SZ 4096
#define D_SZ 1024
#define M_SZ (B_SZ * S_SZ)
#define ELEMS_MAT ((size_t)M_SZ * (size_t)D_SZ)   // 16,777,216 elements per QKV matrix

// workspace layout in ushort (bf16) elements
#define OFF_XB ((size_t)0)
#define OFF_Q  (ELEMS_MAT)
#define OFF_K  (2 * ELEMS_MAT)
#define OFF_V  (3 * ELEMS_MAT)
#define OFF_VT (4 * ELEMS_MAT)
#define OFF_WT (5 * ELEMS_MAT)                    // 3 x 1,048,576

#define MFMA16(a, b, c) __builtin_amdgcn_mfma_f32_16x16x32_bf16((a), (b), (c), 0, 0, 0)

static __device__ __forceinline__ unsigned short f2bf(float f) {
  __bf16 h = (__bf16)f;
  return __builtin_bit_cast(unsigned short, h);
}

static __device__ __forceinline__ void async_lds16(const void* g, void* l) {
  __builtin_amdgcn_global_load_lds((__attribute__((address_space(1))) void*)g,
                                   (__attribute__((address_space(3))) void*)l, 16, 0, 0);
}

// ---------------- cast x (fp32 -> bf16), 8 elems/thread ----------------
__global__ void cast_x_kernel(const float* __restrict__ x, unsigned short* __restrict__ xb) {
  size_t i = ((size_t)blockIdx.x * 256 + threadIdx.x) * 8;
  f32x4 a = *(const f32x4*)(x + i);
  f32x4 b = *(const f32x4*)(x + i + 4);
  bf16x8 o;
  o[0] = (__bf16)a[0]; o[1] = (__bf16)a[1]; o[2] = (__bf16)a[2]; o[3] = (__bf16)a[3];
  o[4] = (__bf16)b[0]; o[5] = (__bf16)b[1]; o[6] = (__bf16)b[2]; o[7] = (__bf16)b[3];
  *(bf16x8*)(xb + i) = o;
}

// ---------------- transpose-cast weights: Wt[n][k] = bf16(W[k][n]) ----------------
__global__ void cast_wt_kernel(const float* __restrict__ Wq, const float* __restrict__ Wk,
                               const float* __restrict__ Wv, unsigned short* __restrict__ Wt) {
  __shared__ float tl[64][65];
  const float* W = blockIdx.z == 0 ? Wq : (blockIdx.z == 1 ? Wk : Wv);
  unsigned short* out = Wt + (size_t)blockIdx.z * (size_t)D_SZ * (size_t)D_SZ;
  const int k0 = blockIdx.x * 64, n0 = blockIdx.y * 64;
  const int t = threadIdx.x;
  for (int i = t; i < 4096; i += 256) {
    int r = i >> 6, c = i & 63;
    tl[r][c] = W[(size_t)(k0 + r) * D_SZ + n0 + c];
  }
  __syncthreads();
  for (int i = t; i < 4096; i += 256) {
    int r = i >> 6, c = i & 63;
    out[(size_t)(n0 + r) * D_SZ + k0 + c] = f2bf(tl[c][r]);
  }
}

// ---------------- bf16 GEMM: Out[z] = xb @ W[z]  (Wt is B^T layout [N][K]) ----------------
// 128x128 tile, BK=64, 4 waves, global_load_lds width-16 staging (m97 structure)
__global__ __launch_bounds__(256) void gemm_kernel(const unsigned short* __restrict__ A,
                                                   const unsigned short* __restrict__ Wt,
                                                   unsigned short* __restrict__ Out) {
  __shared__ unsigned short As[128 * 64];
  __shared__ unsigned short Bs[128 * 64];
  const int t = threadIdx.x;
  const int lr = t & 15;
  const int hi = (t >> 4) & 3;
  const int w = t >> 6, wm = w >> 1, wn = w & 1;
  const size_t m0 = (size_t)blockIdx.x * 128, n0 = (size_t)blockIdx.y * 128;
  const int z = blockIdx.z;
  const char* Ab = (const char*)A;
  const char* Bb = (const char*)(Wt + (size_t)z * (size_t)D_SZ * (size_t)D_SZ);
  unsigned short* OutZ = Out + (size_t)z * ELEMS_MAT;

  const f32x4 z4 = {0.f, 0.f, 0.f, 0.f};
  f32x4 acc[4][4];
#pragma unroll
  for (int mi = 0; mi < 4; ++mi)
#pragma unroll
    for (int ni = 0; ni < 4; ++ni) acc[mi][ni] = z4;

  for (int kt = 0; kt < 16; ++kt) {
#pragma unroll
    for (int p = 0; p < 4; ++p) {
      int off = p * 4096 + t * 16;
      int row = off >> 7, col = off & 127;
      async_lds16(Ab + (m0 + row) * 2048 + kt * 128 + col, (char*)As + off);
      async_lds16(Bb + (n0 + row) * 2048 + kt * 128 + col, (char*)Bs + off);
    }
    __syncthreads();
#pragma unroll
    for (int kk = 0; kk < 2; ++kk) {
      bf16x8 af[4], bfr[4];
#pragma unroll
      for (int mi = 0; mi < 4; ++mi)
        af[mi] = *(const bf16x8*)((const char*)As + (wm * 64 + 16 * mi + lr) * 128 + kk * 64 + hi * 16);
#pragma unroll
      for (int ni = 0; ni < 4; ++ni)
        bfr[ni] = *(const bf16x8*)((const char*)Bs + (wn * 64 + 16 * ni + lr) * 128 + kk * 64 + hi * 16);
#pragma unroll
      for (int mi = 0; mi < 4; ++mi)
#pragma unroll
        for (int ni = 0; ni < 4; ++ni) acc[mi][ni] = MFMA16(af[mi], bfr[ni], acc[mi][ni]);
    }
    __syncthreads();
  }
#pragma unroll
  for (int mi = 0; mi < 4; ++mi)
#pragma unroll
    for (int ni = 0; ni < 4; ++ni)
#pragma unroll
      for (int j = 0; j < 4; ++j)
        OutZ[(m0 + wm * 64 + 16 * mi + hi * 4 + j) * D_SZ + n0 + wn * 64 + 16 * ni + lr] =
            f2bf(acc[mi][ni][j]);
}

// ---------------- transpose V: Vt[b][d][s] = V[b][s][d] ----------------
__global__ void transpose_v_kernel(const unsigned short* __restrict__ V,
                                   unsigned short* __restrict__ Vt) {
  __shared__ unsigned short tl[64][65];
  const int s0 = blockIdx.x * 64, d0 = blockIdx.y * 64, b = blockIdx.z;
  const int t = threadIdx.x;
  const unsigned short* Vb = V + (size_t)b * S_SZ * D_SZ;
  unsigned short* Vo = Vt + (size_t)b * D_SZ * S_SZ;
  for (int i = t; i < 4096; i += 256) {
    int r = i >> 6, c = i & 63;
    tl[r][c] = Vb[(size_t)(s0 + r) * D_SZ + d0 + c];
  }
  __syncthreads();
  for (int i = t; i < 4096; i += 256) {
    int r = i >> 6, c = i & 63;
    Vo[(size_t)(d0 + r) * S_SZ + s0 + c] = tl[c][r];
  }
}

// ---------------- causal flash attention ----------------
// block: 512 threads (8 waves). Q-tile = 32 rows, KV-tile = 64.
// QK^T: each wave reduces a 128-wide D-slice; partials summed via LDS.
// softmax: 512 threads = 32 rows x 16 threads (4 cols each), online m/l.
// PV: each wave owns a 128-wide output-D slice; P via LDS as bf16 frags; V from Vt (contig).
#define KVBLK 64
__global__ __launch_bounds__(512, 2) void attn_kernel(const unsigned short* __restrict__ Qb,
                                                      const unsigned short* __restrict__ Kb,
                                                      const unsigned short* __restrict__ Vt,
                                                      float* __restrict__ out) {
  __shared__ float sh_part[8 * 32 * 68];   // [wave][row][col(64, pad to 68)]
  __shared__ unsigned short sh_P[32 * 72]; // [row][col(64, pad to 72)] bf16
  __shared__ float sh_m[32], sh_l[32], sh_alpha[32];

  const int tid = threadIdx.x;
  const int w = tid >> 6, lane = tid & 63, hi = lane >> 4, lr = lane & 15;
  const int bx = blockIdx.x;
  const int xcd = bx & 7, ix = bx >> 3;
  const int b = xcd >> 1;                       // batch pinned to an XCD pair
  const int qt = 127 - (2 * ix + (xcd & 1));    // heaviest q-tiles first
  const int q0 = qt * 32;

  if (tid < 32) { sh_m[tid] = -1e30f; sh_l[tid] = 0.f; }

  const unsigned short* Qp = Qb + ((size_t)b * S_SZ + q0) * D_SZ;
  const unsigned short* Kp = Kb + (size_t)b * S_SZ * D_SZ;
  const unsigned short* Vp = Vt + (size_t)b * D_SZ * S_SZ;

  // Q fragments for this wave's 128-wide D-slice, held in registers
  bf16x8 qf[2][4];
#pragma unroll
  for (int mi = 0; mi < 2; ++mi)
#pragma unroll
    for (int kk = 0; kk < 4; ++kk)
      qf[mi][kk] = *(const bf16x8*)(Qp + (size_t)(16 * mi + lr) * D_SZ + w * 128 + kk * 32 + hi * 8);

  const f32x4 z4 = {0.f, 0.f, 0.f, 0.f};
  f32x4 o[2][8];
#pragma unroll
  for (int mi = 0; mi < 2; ++mi)
#pragma unroll
    for (int ni = 0; ni < 8; ++ni) o[mi][ni] = z4;

  const int ntile = (q0 + 31) / KVBLK + 1;
  const int r = tid >> 4, cg = tid & 15, c0 = (tid & 15) * 4;

  for (int kt = 0; kt < ntile; ++kt) {
    const int kv0 = kt * KVBLK;
    // ---- QK^T partial over this wave's D-slice ----
    f32x4 sacc[2][4];
#pragma unroll
    for (int mi = 0; mi < 2; ++mi)
#pragma unroll
      for (int ni = 0; ni < 4; ++ni) sacc[mi][ni] = z4;
#pragma unroll
    for (int kk = 0; kk < 4; ++kk) {
      bf16x8 kb[4];
#pragma unroll
      for (int ni = 0; ni < 4; ++ni)
        kb[ni] = *(const bf16x8*)(Kp + (size_t)(kv0 + 16 * ni + lr) * D_SZ + w * 128 + kk * 32 + hi * 8);
#pragma unroll
      for (int mi = 0; mi < 2; ++mi)
#pragma unroll
        for (int ni = 0; ni < 4; ++ni) sacc[mi][ni] = MFMA16(qf[mi][kk], kb[ni], sacc[mi][ni]);
    }
    // write partials
#pragma unroll
    for (int mi = 0; mi < 2; ++mi)
#pragma unroll
      for (int ni = 0; ni < 4; ++ni)
#pragma unroll
        for (int j = 0; j < 4; ++j)
          sh_part[w * 2176 + (16 * mi + hi * 4 + j) * 68 + 16 * ni + lr] = sacc[mi][ni][j];
    __syncthreads();

    // ---- reduce + online softmax (all 512 threads; row r, 4 cols) ----
    f32x4 s = z4;
#pragma unroll
    for (int w8 = 0; w8 < 8; ++w8) s += *(const f32x4*)&sh_part[w8 * 2176 + r * 68 + c0];
    s = s * 0.03125f;  // 1/sqrt(1024)
    const int qrow = q0 + r;
#pragma unroll
    for (int j = 0; j < 4; ++j)
      if (kv0 + c0 + j > qrow) s[j] = -1e30f;
    float tmax = fmaxf(fmaxf(s[0], s[1]), fmaxf(s[2], s[3]));
    tmax = fmaxf(tmax, __shfl_xor(tmax, 1));
    tmax = fmaxf(tmax, __shfl_xor(tmax, 2));
    tmax = fmaxf(tmax, __shfl_xor(tmax, 4));
    tmax = fmaxf(tmax, __shfl_xor(tmax, 8));
    const float m_old = sh_m[r];
    const float m_new = fmaxf(m_old, tmax);
    const float alpha = __expf(m_old - m_new);
    f32x4 p;
#pragma unroll
    for (int j = 0; j < 4; ++j) p[j] = __expf(s[j] - m_new);
    float ps = p[0] + p[1] + p[2] + p[3];
    ps += __shfl_xor(ps, 1);
    ps += __shfl_xor(ps, 2);
    ps += __shfl_xor(ps, 4);
    ps += __shfl_xor(ps, 8);
    if (cg == 0) {
      sh_l[r] = sh_l[r] * alpha + ps;
      sh_m[r] = m_new;
      sh_alpha[r] = alpha;
    }
    ushort4 pk;
    pk.x = f2bf(p[0]); pk.y = f2bf(p[1]); pk.z = f2bf(p[2]); pk.w = f2bf(p[3]);
    *(ushort4*)&sh_P[r * 72 + c0] = pk;
    __syncthreads();

    // ---- rescale O and accumulate PV ----
    float av[2][4];
#pragma unroll
    for (int mi = 0; mi < 2; ++mi)
#pragma unroll
      for (int j = 0; j < 4; ++j) av[mi][j] = sh_alpha[16 * mi + hi * 4 + j];
#pragma unroll
    for (int mi = 0; mi < 2; ++mi)
#pragma unroll
      for (int ni = 0; ni < 8; ++ni)
#pragma unroll
        for (int j = 0; j < 4; ++j) o[mi][ni][j] *= av[mi][j];
#pragma unroll
    for (int kk = 0; kk < 2; ++kk) {
      bf16x8 pa[2];
#pragma unroll
      for (int mi = 0; mi < 2; ++mi)
        pa[mi] = *(const bf16x8*)&sh_P[(16 * mi + lr) * 72 + kk * 32 + hi * 8];
#pragma unroll
      for (int ni = 0; ni < 8; ++ni) {
        bf16x8 vb = *(const bf16x8*)(Vp + (size_t)(w * 128 + 16 * ni + lr) * S_SZ + kv0 + kk * 32 + hi * 8);
#pragma unroll
        for (int mi = 0; mi < 2; ++mi) o[mi][ni] = MFMA16(pa[mi], vb, o[mi][ni]);
      }
    }
  }

  // ---- epilogue: divide by l, write fp32 ----
  float li[2][4];
#pragma unroll
  for (int mi = 0; mi < 2; ++mi)
#pragma unroll
    for (int j = 0; j < 4; ++j) li[mi][j] = 1.0f / sh_l[16 * mi + hi * 4 + j];
#pragma unroll
  for (int mi = 0; mi < 2; ++mi)
#pragma unroll
    for (int ni = 0; ni < 8; ++ni)
#pragma unroll
      for (int j = 0; j < 4; ++j)
        out[((size_t)b * S_SZ + q0 + 16 * mi + hi * 4 + j) * D_SZ + w * 128 + 16 * ni + lr] =
            o[mi][ni][j] * li[mi][j];
}

extern "C" void kernel_launch(void* const* d_in, const int* in_sizes, int n_in,
                              void* d_out, int out_size, void* d_ws, size_t ws_size,
                              hipStream_t stream) {
  (void)in_sizes; (void)n_in; (void)out_size; (void)ws_size;
  const float* x  = (const float*)d_in[0];
  const float* Wq = (const float*)d_in[1];
  const float* Wk = (const float*)d_in[2];
  const float* Wv = (const float*)d_in[3];
  float* out = (float*)d_out;
  unsigned short* ws = (unsigned short*)d_ws;
  unsigned short* xb = ws + OFF_XB;
  unsigned short* qb = ws + OFF_Q;   // q,k,v contiguous: gemm z-indexes into this
  unsigned short* vb = ws + OFF_V;
  unsigned short* vt = ws + OFF_VT;
  unsigned short* wt = ws + OFF_WT;

  cast_x_kernel<<<(int)(ELEMS_MAT / (256 * 8)), 256, 0, stream>>>(x, xb);
  cast_wt_kernel<<<dim3(16, 16, 3), 256, 0, stream>>>(Wq, Wk, Wv, wt);
  gemm_kernel<<<dim3(128, 8, 3), 256, 0, stream>>>(xb, wt, qb);
  transpose_v_kernel<<<dim3(64, 16, 4), 256, 0, stream>>>(vb, vt);
  attn_kernel<<<512, 512, 0, stream>>>(qb, ws + OFF_K, vt, out);
}

// Round 2
// 448.716 us; speedup vs baseline: 1.6849x; 1.6849x over previous
//
#include <hip/hip_runtime.h>

typedef __bf16 bf16x8 __attribute__((ext_vector_type(8)));
typedef float f32x4 __attribute__((ext_vector_type(4)));

#define B_SZ 4
#define S_SZ 4096
#define D_SZ 1024
#define ELEMS_MAT ((size_t)B_SZ * S_SZ * D_SZ)   // 16,777,216

// ---- workspace layout (ushort elems), total 174 MB (same as round-1 proven size) ----
// Persistent: Q, K, Vt. ZONE holds xb, V, Wt early; S-packed aliases ZONE later.
#define OFF_Q  ((size_t)0)
#define OFF_K  (ELEMS_MAT)
#define OFF_VT (2 * ELEMS_MAT)
#define ZONE   (3 * ELEMS_MAT)
#define OFF_XB (ZONE)
#define OFF_V  (ZONE + ELEMS_MAT)
#define OFF_WT (ZONE + 2 * ELEMS_MAT)
#define OFF_S  (ZONE)                             // aliases xb+V+Wt (dead by then)
#define S_BATCH ((size_t)8650752)                 // 528 tiles * 128*128 elems

#define MFMA16(a, b, c) __builtin_amdgcn_mfma_f32_16x16x32_bf16((a), (b), (c), 0, 0, 0)

static __device__ __forceinline__ unsigned short f2bf(float f) {
  __bf16 h = (__bf16)f;
  return __builtin_bit_cast(unsigned short, h);
}
static __device__ __forceinline__ float bf2f(unsigned short u) {
  return (float)__builtin_bit_cast(__bf16, u);
}

static __device__ __forceinline__ void async_lds16(const void* g, void* l) {
  __builtin_amdgcn_global_load_lds((__attribute__((address_space(1))) void*)g,
                                   (__attribute__((address_space(3))) void*)l, 16, 0, 0);
}

// ---------------- cast x (fp32 -> bf16), 8 elems/thread ----------------
__global__ void cast_x_kernel(const float* __restrict__ x, unsigned short* __restrict__ xb) {
  size_t i = ((size_t)blockIdx.x * 256 + threadIdx.x) * 8;
  f32x4 a = *(const f32x4*)(x + i);
  f32x4 b = *(const f32x4*)(x + i + 4);
  bf16x8 o;
  o[0] = (__bf16)a[0]; o[1] = (__bf16)a[1]; o[2] = (__bf16)a[2]; o[3] = (__bf16)a[3];
  o[4] = (__bf16)b[0]; o[5] = (__bf16)b[1]; o[6] = (__bf16)b[2]; o[7] = (__bf16)b[3];
  *(bf16x8*)(xb + i) = o;
}

// ---------------- transpose-cast weights: Wt[n][k] = bf16(W[k][n]) ----------------
__global__ void cast_wt_kernel(const float* __restrict__ Wq, const float* __restrict__ Wk,
                               const float* __restrict__ Wv, unsigned short* __restrict__ Wt) {
  __shared__ float tl[64][65];
  const float* W = blockIdx.z == 0 ? Wq : (blockIdx.z == 1 ? Wk : Wv);
  unsigned short* out = Wt + (size_t)blockIdx.z * (size_t)D_SZ * (size_t)D_SZ;
  const int k0 = blockIdx.x * 64, n0 = blockIdx.y * 64;
  const int t = threadIdx.x;
  for (int i = t; i < 4096; i += 256) {
    int r = i >> 6, c = i & 63;
    tl[r][c] = W[(size_t)(k0 + r) * D_SZ + n0 + c];
  }
  __syncthreads();
  for (int i = t; i < 4096; i += 256) {
    int r = i >> 6, c = i & 63;
    out[(size_t)(n0 + r) * D_SZ + k0 + c] = f2bf(tl[c][r]);
  }
}

// ---------------- QKV projection GEMM (m97 128x128 structure) ----------------
__global__ __launch_bounds__(256) void gemm_qkv_kernel(const unsigned short* __restrict__ A,
                                                       const unsigned short* __restrict__ Wt,
                                                       unsigned short* __restrict__ Q,
                                                       unsigned short* __restrict__ K,
                                                       unsigned short* __restrict__ V) {
  __shared__ unsigned short As[128 * 64];
  __shared__ unsigned short Bs[128 * 64];
  const int t = threadIdx.x;
  const int lr = t & 15, hi = (t >> 4) & 3;
  const int w = t >> 6, wm = w >> 1, wn = w & 1;
  const size_t m0 = (size_t)blockIdx.x * 128, n0 = (size_t)blockIdx.y * 128;
  const int z = blockIdx.z;
  const char* Ab = (const char*)A;
  const char* Bb = (const char*)(Wt + (size_t)z * (size_t)D_SZ * (size_t)D_SZ);
  unsigned short* OutZ = z == 0 ? Q : (z == 1 ? K : V);

  const f32x4 z4 = {0.f, 0.f, 0.f, 0.f};
  f32x4 acc[4][4];
#pragma unroll
  for (int mi = 0; mi < 4; ++mi)
#pragma unroll
    for (int ni = 0; ni < 4; ++ni) acc[mi][ni] = z4;

  for (int kt = 0; kt < 16; ++kt) {
#pragma unroll
    for (int p = 0; p < 4; ++p) {
      int off = p * 4096 + t * 16;
      int row = off >> 7, col = off & 127;
      async_lds16(Ab + (m0 + row) * 2048 + kt * 128 + col, (char*)As + off);
      async_lds16(Bb + (n0 + row) * 2048 + kt * 128 + col, (char*)Bs + off);
    }
    __syncthreads();
#pragma unroll
    for (int kk = 0; kk < 2; ++kk) {
      bf16x8 af[4], bfr[4];
#pragma unroll
      for (int mi = 0; mi < 4; ++mi)
        af[mi] = *(const bf16x8*)((const char*)As + (wm * 64 + 16 * mi + lr) * 128 + kk * 64 + hi * 16);
#pragma unroll
      for (int ni = 0; ni < 4; ++ni)
        bfr[ni] = *(const bf16x8*)((const char*)Bs + (wn * 64 + 16 * ni + lr) * 128 + kk * 64 + hi * 16);
#pragma unroll
      for (int mi = 0; mi < 4; ++mi)
#pragma unroll
        for (int ni = 0; ni < 4; ++ni) acc[mi][ni] = MFMA16(af[mi], bfr[ni], acc[mi][ni]);
    }
    __syncthreads();
  }
#pragma unroll
  for (int mi = 0; mi < 4; ++mi)
#pragma unroll
    for (int ni = 0; ni < 4; ++ni)
#pragma unroll
      for (int j = 0; j < 4; ++j)
        OutZ[(m0 + wm * 64 + 16 * mi + hi * 4 + j) * D_SZ + n0 + wn * 64 + 16 * ni + lr] =
            f2bf(acc[mi][ni][j]);
}

// ---------------- transpose V: Vt[b][d][s] = V[b][s][d] ----------------
__global__ void transpose_v_kernel(const unsigned short* __restrict__ V,
                                   unsigned short* __restrict__ Vt) {
  __shared__ unsigned short tl[64][65];
  const int s0 = blockIdx.x * 64, d0 = blockIdx.y * 64, b = blockIdx.z;
  const int t = threadIdx.x;
  const unsigned short* Vb = V + (size_t)b * S_SZ * D_SZ;
  unsigned short* Vo = Vt + (size_t)b * D_SZ * S_SZ;
  for (int i = t; i < 4096; i += 256) {
    int r = i >> 6, c = i & 63;
    tl[r][c] = Vb[(size_t)(s0 + r) * D_SZ + d0 + c];
  }
  __syncthreads();
  for (int i = t; i < 4096; i += 256) {
    int r = i >> 6, c = i & 63;
    Vo[(size_t)(d0 + r) * S_SZ + s0 + c] = tl[c][r];
  }
}

// ---------------- S = (Q K^T)/32, lower-triangle 128x128 tiles, packed ----------------
// Packed layout per batch: row-block i (0..31) at tile-offset i*(i+1)/2*16384,
// stored [128 rows][(i+1)*128 cols] row-major.
__global__ __launch_bounds__(256) void s_gemm_kernel(const unsigned short* __restrict__ Q,
                                                     const unsigned short* __restrict__ K,
                                                     unsigned short* __restrict__ Sp) {
  __shared__ unsigned short As[128 * 64];
  __shared__ unsigned short Bs[128 * 64];
  const int t = threadIdx.x;
  const int lr = t & 15, hi = (t >> 4) & 3;
  const int w = t >> 6, wm = w >> 1, wn = w & 1;
  const int tile = blockIdx.x, b = blockIdx.y;
  int i = (int)((sqrtf(8.0f * tile + 1.0f) - 1.0f) * 0.5f);
  while ((i + 1) * (i + 2) / 2 <= tile) ++i;
  while (i * (i + 1) / 2 > tile) --i;
  const int j = tile - i * (i + 1) / 2;

  const char* Ab = (const char*)(Q + ((size_t)b * S_SZ + (size_t)i * 128) * D_SZ);
  const char* Bb = (const char*)(K + ((size_t)b * S_SZ + (size_t)j * 128) * D_SZ);
  const int L = (i + 1) * 128;
  unsigned short* So = Sp + (size_t)b * S_BATCH + (size_t)(i * (i + 1) / 2) * 16384;

  const f32x4 z4 = {0.f, 0.f, 0.f, 0.f};
  f32x4 acc[4][4];
#pragma unroll
  for (int mi = 0; mi < 4; ++mi)
#pragma unroll
    for (int ni = 0; ni < 4; ++ni) acc[mi][ni] = z4;

  for (int kt = 0; kt < 16; ++kt) {
#pragma unroll
    for (int p = 0; p < 4; ++p) {
      int off = p * 4096 + t * 16;
      int row = off >> 7, col = off & 127;
      async_lds16(Ab + (size_t)row * 2048 + kt * 128 + col, (char*)As + off);
      async_lds16(Bb + (size_t)row * 2048 + kt * 128 + col, (char*)Bs + off);
    }
    __syncthreads();
#pragma unroll
    for (int kk = 0; kk < 2; ++kk) {
      bf16x8 af[4], bfr[4];
#pragma unroll
      for (int mi = 0; mi < 4; ++mi)
        af[mi] = *(const bf16x8*)((const char*)As + (wm * 64 + 16 * mi + lr) * 128 + kk * 64 + hi * 16);
#pragma unroll
      for (int ni = 0; ni < 4; ++ni)
        bfr[ni] = *(const bf16x8*)((const char*)Bs + (wn * 64 + 16 * ni + lr) * 128 + kk * 64 + hi * 16);
#pragma unroll
      for (int mi = 0; mi < 4; ++mi)
#pragma unroll
        for (int ni = 0; ni < 4; ++ni) acc[mi][ni] = MFMA16(af[mi], bfr[ni], acc[mi][ni]);
    }
    __syncthreads();
  }
#pragma unroll
  for (int mi = 0; mi < 4; ++mi)
#pragma unroll
    for (int ni = 0; ni < 4; ++ni)
#pragma unroll
      for (int jj = 0; jj < 4; ++jj) {
        const int mm = wm * 64 + 16 * mi + hi * 4 + jj;
        const int nn = wn * 64 + 16 * ni + lr;
        float val = acc[mi][ni][jj] * 0.03125f;                 // 1/sqrt(1024)
        if (j * 128 + nn > i * 128 + mm) val = -1e30f;          // causal mask
        So[(size_t)mm * L + j * 128 + nn] = f2bf(val);
      }
}

// ---------------- row softmax in place on packed S (wave per row) ----------------
__global__ __launch_bounds__(256) void softmax_kernel(unsigned short* __restrict__ Sp) {
  const int w = threadIdx.x >> 6, lane = threadIdx.x & 63;
  const int rowflat = blockIdx.x * 4 + w;
  const int rr = 16383 - rowflat;              // heavy rows first
  const int b = rr >> 12, q = rr & 4095;
  const int i = q >> 7;
  const int L = (i + 1) << 7;
  unsigned short* base = Sp + (size_t)b * S_BATCH + (size_t)(i * (i + 1) / 2) * 16384 +
                         (size_t)(q & 127) * L;
  const int niter = (L + 511) >> 9;            // chunks of 512 elems (64 lanes x 8)
  const __bf16 NEG = (__bf16)(-1e30f);
  bf16x8 v[8];
#pragma unroll
  for (int jt = 0; jt < 8; ++jt) {
    if (jt < niter) {
      const int off = jt * 512 + lane * 8;
      if (off < L) v[jt] = *(const bf16x8*)(base + off);
      else { bf16x8 f; f[0]=NEG;f[1]=NEG;f[2]=NEG;f[3]=NEG;f[4]=NEG;f[5]=NEG;f[6]=NEG;f[7]=NEG; v[jt] = f; }
    }
  }
  float m = -1e30f;
#pragma unroll
  for (int jt = 0; jt < 8; ++jt)
    if (jt < niter)
#pragma unroll
      for (int e = 0; e < 8; ++e) m = fmaxf(m, (float)v[jt][e]);
  m = fmaxf(m, __shfl_xor(m, 1));  m = fmaxf(m, __shfl_xor(m, 2));
  m = fmaxf(m, __shfl_xor(m, 4));  m = fmaxf(m, __shfl_xor(m, 8));
  m = fmaxf(m, __shfl_xor(m, 16)); m = fmaxf(m, __shfl_xor(m, 32));
  float l = 0.f;
#pragma unroll
  for (int jt = 0; jt < 8; ++jt)
    if (jt < niter)
#pragma unroll
      for (int e = 0; e < 8; ++e) l += __expf((float)v[jt][e] - m);
  l += __shfl_xor(l, 1);  l += __shfl_xor(l, 2);  l += __shfl_xor(l, 4);
  l += __shfl_xor(l, 8);  l += __shfl_xor(l, 16); l += __shfl_xor(l, 32);
  const float rl = 1.0f / l;
#pragma unroll
  for (int jt = 0; jt < 8; ++jt) {
    if (jt < niter) {
      const int off = jt * 512 + lane * 8;
      if (off < L) {
        bf16x8 p;
#pragma unroll
        for (int e = 0; e < 8; ++e) p[e] = (__bf16)(__expf((float)v[jt][e] - m) * rl);
        *(bf16x8*)(base + off) = p;
      }
    }
  }
}

// ---------------- O = P V  (A = packed P row-block, B^T = Vt) ----------------
__global__ __launch_bounds__(256) void pv_kernel(const unsigned short* __restrict__ Sp,
                                                 const unsigned short* __restrict__ Vt,
                                                 float* __restrict__ out) {
  __shared__ unsigned short As[128 * 64];
  __shared__ unsigned short Bs[128 * 64];
  const int t = threadIdx.x;
  const int lr = t & 15, hi = (t >> 4) & 3;
  const int w = t >> 6, wm = w >> 1, wn = w & 1;
  const int bid = blockIdx.x;
  const int i = 31 - (bid >> 5);               // heavy row-blocks first
  const int sub = bid & 31;
  const int b = sub >> 3, cb = sub & 7;

  const char* Ab = (const char*)(Sp + (size_t)b * S_BATCH + (size_t)(i * (i + 1) / 2) * 16384);
  const size_t ldaB = (size_t)(i + 1) * 256;   // bytes
  const char* Bb = (const char*)(Vt + ((size_t)b * D_SZ + (size_t)cb * 128) * S_SZ);
  const int nkt = 2 * (i + 1);

  const f32x4 z4 = {0.f, 0.f, 0.f, 0.f};
  f32x4 acc[4][4];
#pragma unroll
  for (int mi = 0; mi < 4; ++mi)
#pragma unroll
    for (int ni = 0; ni < 4; ++ni) acc[mi][ni] = z4;

  for (int kt = 0; kt < nkt; ++kt) {
#pragma unroll
    for (int p = 0; p < 4; ++p) {
      int off = p * 4096 + t * 16;
      int row = off >> 7, col = off & 127;
      async_lds16(Ab + (size_t)row * ldaB + kt * 128 + col, (char*)As + off);
      async_lds16(Bb + (size_t)row * 8192 + kt * 128 + col, (char*)Bs + off);
    }
    __syncthreads();
#pragma unroll
    for (int kk = 0; kk < 2; ++kk) {
      bf16x8 af[4], bfr[4];
#pragma unroll
      for (int mi = 0; mi < 4; ++mi)
        af[mi] = *(const bf16x8*)((const char*)As + (wm * 64 + 16 * mi + lr) * 128 + kk * 64 + hi * 16);
#pragma unroll
      for (int ni = 0; ni < 4; ++ni)
        bfr[ni] = *(const bf16x8*)((const char*)Bs + (wn * 64 + 16 * ni + lr) * 128 + kk * 64 + hi * 16);
#pragma unroll
      for (int mi = 0; mi < 4; ++mi)
#pragma unroll
        for (int ni = 0; ni < 4; ++ni) acc[mi][ni] = MFMA16(af[mi], bfr[ni], acc[mi][ni]);
    }
    __syncthreads();
  }
#pragma unroll
  for (int mi = 0; mi < 4; ++mi)
#pragma unroll
    for (int ni = 0; ni < 4; ++ni)
#pragma unroll
      for (int jj = 0; jj < 4; ++jj)
        out[((size_t)b * S_SZ + (size_t)i * 128 + wm * 64 + 16 * mi + hi * 4 + jj) * D_SZ +
            cb * 128 + wn * 64 + 16 * ni + lr] = acc[mi][ni][jj];
}

extern "C" void kernel_launch(void* const* d_in, const int* in_sizes, int n_in,
                              void* d_out, int out_size, void* d_ws, size_t ws_size,
                              hipStream_t stream) {
  (void)in_sizes; (void)n_in; (void)out_size; (void)ws_size;
  const float* x  = (const float*)d_in[0];
  const float* Wq = (const float*)d_in[1];
  const float* Wk = (const float*)d_in[2];
  const float* Wv = (const float*)d_in[3];
  float* out = (float*)d_out;
  unsigned short* ws = (unsigned short*)d_ws;

  cast_x_kernel<<<8192, 256, 0, stream>>>(x, ws + OFF_XB);
  cast_wt_kernel<<<dim3(16, 16, 3), 256, 0, stream>>>(Wq, Wk, Wv, ws + OFF_WT);
  gemm_qkv_kernel<<<dim3(128, 8, 3), 256, 0, stream>>>(ws + OFF_XB, ws + OFF_WT,
                                                       ws + OFF_Q, ws + OFF_K, ws + OFF_V);
  transpose_v_kernel<<<dim3(64, 16, 4), 256, 0, stream>>>(ws + OFF_V, ws + OFF_VT);
  // S-pass aliases the zone (xb, V, Wt all dead after the two kernels above)
  s_gemm_kernel<<<dim3(528, 4), 256, 0, stream>>>(ws + OFF_Q, ws + OFF_K, ws + OFF_S);
  softmax_kernel<<<4096, 256, 0, stream>>>(ws + OFF_S);
  pv_kernel<<<1024, 256, 0, stream>>>(ws + OFF_S, ws + OFF_VT, out);
}

// Round 3
// 404.003 us; speedup vs baseline: 1.8714x; 1.1107x over previous
//
#include <hip/hip_runtime.h>

typedef __bf16 bf16x8 __attribute__((ext_vector_type(8)));
typedef float f32x4 __attribute__((ext_vector_type(4)));

#define B_SZ 4
#define S_SZ 4096
#define D_SZ 1024
#define ELEMS_MAT ((size_t)B_SZ * S_SZ * D_SZ)   // 16,777,216

// ---- workspace layout (ushort elems), 174 MB total (identical to proven r1/r2 size) ----
#define OFF_Q  ((size_t)0)
#define OFF_K  (ELEMS_MAT)
#define OFF_VT (2 * ELEMS_MAT)
#define ZONE   (3 * ELEMS_MAT)
#define OFF_XB (ZONE)
#define OFF_V  (ZONE + ELEMS_MAT)
#define OFF_WT (ZONE + 2 * ELEMS_MAT)
#define OFF_S  (ZONE)                             // aliases xb+V+Wt (dead by then)
// S packed per batch: 16 row-blocks of 256 rows; block I at tri(I)*65536, row len (I+1)*256
#define S_BATCH ((size_t)8912896)                 // 136 tiles * 256*256

#define MFMA16(a, b, c) __builtin_amdgcn_mfma_f32_16x16x32_bf16((a), (b), (c), 0, 0, 0)

static __device__ __forceinline__ unsigned short f2bf(float f) {
  __bf16 h = (__bf16)f;
  return __builtin_bit_cast(unsigned short, h);
}

static __device__ __forceinline__ void async_lds16(const void* g, void* l) {
  __builtin_amdgcn_global_load_lds((__attribute__((address_space(1))) void*)g,
                                   (__attribute__((address_space(3))) void*)l, 16, 0, 0);
}

// ---------------- cast x (fp32 -> bf16) ----------------
__global__ void cast_x_kernel(const float* __restrict__ x, unsigned short* __restrict__ xb) {
  size_t i = ((size_t)blockIdx.x * 256 + threadIdx.x) * 8;
  f32x4 a = *(const f32x4*)(x + i);
  f32x4 b = *(const f32x4*)(x + i + 4);
  bf16x8 o;
  o[0] = (__bf16)a[0]; o[1] = (__bf16)a[1]; o[2] = (__bf16)a[2]; o[3] = (__bf16)a[3];
  o[4] = (__bf16)b[0]; o[5] = (__bf16)b[1]; o[6] = (__bf16)b[2]; o[7] = (__bf16)b[3];
  *(bf16x8*)(xb + i) = o;
}

// ---------------- transpose-cast weights: Wt[n][k] = bf16(W[k][n]); Wt = [3072][1024] ----------------
__global__ void cast_wt_kernel(const float* __restrict__ Wq, const float* __restrict__ Wk,
                               const float* __restrict__ Wv, unsigned short* __restrict__ Wt) {
  __shared__ float tl[64][65];
  const float* W = blockIdx.z == 0 ? Wq : (blockIdx.z == 1 ? Wk : Wv);
  unsigned short* out = Wt + (size_t)blockIdx.z * (size_t)D_SZ * (size_t)D_SZ;
  const int k0 = blockIdx.x * 64, n0 = blockIdx.y * 64;
  const int t = threadIdx.x;
  for (int i = t; i < 4096; i += 256) {
    int r = i >> 6, c = i & 63;
    tl[r][c] = W[(size_t)(k0 + r) * D_SZ + n0 + c];
  }
  __syncthreads();
  for (int i = t; i < 4096; i += 256) {
    int r = i >> 6, c = i & 63;
    out[(size_t)(n0 + r) * D_SZ + k0 + c] = f2bf(tl[c][r]);
  }
}

// ================= 256x256xBK64 8-wave GEMM template (T2+T4+T5) =================
// LDS tile: [256 rows][64 bf16] row-major (128B/row), byte swizzle: b ^= (row&7)<<4.
// Staging writes LDS linearly (global_load_lds) with inverse-permuted global source.
static __device__ __forceinline__ void stage_tile(const char* Asrc, size_t lda,
                                                  const char* Bsrc, size_t ldb,
                                                  unsigned short* ldsA, unsigned short* ldsB,
                                                  int tid) {
#pragma unroll
  for (int it = 0; it < 4; ++it) {
    int i = it * 512 + tid;
    int row = i >> 3;
    int scol = ((i & 7) ^ (row & 7)) << 4;
    async_lds16(Asrc + (size_t)row * lda + scol, (char*)ldsA + i * 16);
  }
#pragma unroll
  for (int it = 0; it < 4; ++it) {
    int i = it * 512 + tid;
    int row = i >> 3;
    int scol = ((i & 7) ^ (row & 7)) << 4;
    async_lds16(Bsrc + (size_t)row * ldb + scol, (char*)ldsB + i * 16);
  }
}

static __device__ __forceinline__ void compute_tile(const unsigned short* As,
                                                    const unsigned short* Bs,
                                                    int wm, int wn, int lr, int hi,
                                                    f32x4 acc[8][4]) {
  const char* Ab = (const char*)As;
  const char* Bb = (const char*)Bs;
#pragma unroll
  for (int q = 0; q < 4; ++q) {                 // quadrants: (qm,qn) of wave's 128x64 C
    const int qm = q >> 1, qn = q & 1;
    bf16x8 af[4][2], bfr[2][2];
#pragma unroll
    for (int f = 0; f < 4; ++f) {
      const int r = wm * 128 + (qm * 4 + f) * 16 + lr;
#pragma unroll
      for (int kk = 0; kk < 2; ++kk)
        af[f][kk] = *(const bf16x8*)(Ab + r * 128 + ((kk * 64 + hi * 16) ^ ((r & 7) << 4)));
    }
#pragma unroll
    for (int f = 0; f < 2; ++f) {
      const int r = wn * 64 + (qn * 2 + f) * 16 + lr;
#pragma unroll
      for (int kk = 0; kk < 2; ++kk)
        bfr[f][kk] = *(const bf16x8*)(Bb + r * 128 + ((kk * 64 + hi * 16) ^ ((r & 7) << 4)));
    }
    __builtin_amdgcn_s_setprio(1);
#pragma unroll
    for (int kk = 0; kk < 2; ++kk)
#pragma unroll
      for (int f = 0; f < 4; ++f)
#pragma unroll
        for (int g = 0; g < 2; ++g)
          acc[qm * 4 + f][qn * 2 + g] = MFMA16(af[f][kk], bfr[g][kk], acc[qm * 4 + f][qn * 2 + g]);
    __builtin_amdgcn_s_setprio(0);
  }
}

// Main loop: tile t+1's 8 loads issued at top (into free buffer), then counted
// vmcnt(8) waits only for tile t. 2 raw barriers per K-tile; never vmcnt(0) mid-loop.
static __device__ __forceinline__ void gemm_mainloop(const char* A, size_t lda,
                                                     const char* B, size_t ldb, int NT,
                                                     unsigned short sm[2][2][16384],
                                                     int tid, f32x4 acc[8][4]) {
  const int lane = tid & 63, w = tid >> 6;
  const int wm = w >> 2, wn = w & 3, lr = lane & 15, hi = lane >> 4;
  stage_tile(A, lda, B, ldb, sm[0][0], sm[0][1], tid);
  for (int t = 0; t < NT - 1; ++t) {
    const int cur = t & 1;
    stage_tile(A + (size_t)(t + 1) * 128, lda, B + (size_t)(t + 1) * 128, ldb,
               sm[cur ^ 1][0], sm[cur ^ 1][1], tid);
    asm volatile("s_waitcnt vmcnt(8)" ::: "memory");
    __builtin_amdgcn_s_barrier();
    compute_tile(sm[cur][0], sm[cur][1], wm, wn, lr, hi, acc);
    __builtin_amdgcn_s_barrier();
  }
  asm volatile("s_waitcnt vmcnt(0)" ::: "memory");
  __builtin_amdgcn_s_barrier();
  compute_tile(sm[(NT - 1) & 1][0], sm[(NT - 1) & 1][1], wm, wn, lr, hi, acc);
}

#define GEMM_PRE()                                    \
  __shared__ unsigned short sm[2][2][16384];          \
  const int tid = threadIdx.x;                        \
  f32x4 acc[8][4];                                    \
  {                                                   \
    const f32x4 z4 = {0.f, 0.f, 0.f, 0.f};            \
    _Pragma("unroll") for (int f = 0; f < 8; ++f)     \
      _Pragma("unroll") for (int g = 0; g < 4; ++g)   \
        acc[f][g] = z4;                               \
  }

#define EPI_IDX()                                     \
  const int lane = tid & 63, w = tid >> 6;            \
  const int wm = w >> 2, wn = w & 3;                  \
  const int lr = lane & 15, hi = lane >> 4;

// ---------------- QKV: [16384,1024] x [1024,3072] ----------------
__global__ __launch_bounds__(512, 2) void gemm_qkv256(const unsigned short* __restrict__ xb,
                                                      const unsigned short* __restrict__ Wt,
                                                      unsigned short* __restrict__ Q,
                                                      unsigned short* __restrict__ K,
                                                      unsigned short* __restrict__ V) {
  GEMM_PRE();
  const int bid = blockIdx.x;
  const int sw = (bid & 7) * 96 + (bid >> 3);   // XCD swizzle (768 = 8*96)
  const int mt = sw % 64, nt = sw / 64;         // nt in [0,12)
  const char* A = (const char*)xb + (size_t)mt * 256 * 2048;
  const char* Bp = (const char*)Wt + (size_t)nt * 256 * 2048;
  gemm_mainloop(A, 2048, Bp, 2048, 16, sm, tid, acc);
  EPI_IDX();
  unsigned short* Out = (nt >> 2) == 0 ? Q : ((nt >> 2) == 1 ? K : V);
  const int nb = (nt & 3) * 256;
#pragma unroll
  for (int f = 0; f < 8; ++f)
#pragma unroll
    for (int g = 0; g < 4; ++g)
#pragma unroll
      for (int j = 0; j < 4; ++j) {
        const int m = mt * 256 + wm * 128 + f * 16 + hi * 4 + j;
        const int n = nb + wn * 64 + g * 16 + lr;
        Out[(size_t)m * D_SZ + n] = f2bf(acc[f][g][j]);
      }
}

// ---------------- transpose V: Vt[b][d][s] = V[b][s][d] ----------------
__global__ void transpose_v_kernel(const unsigned short* __restrict__ V,
                                   unsigned short* __restrict__ Vt) {
  __shared__ unsigned short tl[64][65];
  const int s0 = blockIdx.x * 64, d0 = blockIdx.y * 64, b = blockIdx.z;
  const int t = threadIdx.x;
  const unsigned short* Vb = V + (size_t)b * S_SZ * D_SZ;
  unsigned short* Vo = Vt + (size_t)b * D_SZ * S_SZ;
  for (int i = t; i < 4096; i += 256) {
    int r = i >> 6, c = i & 63;
    tl[r][c] = Vb[(size_t)(s0 + r) * D_SZ + d0 + c];
  }
  __syncthreads();
  for (int i = t; i < 4096; i += 256) {
    int r = i >> 6, c = i & 63;
    Vo[(size_t)(d0 + r) * S_SZ + s0 + c] = tl[c][r];
  }
}

// ---------------- S = (Q K^T)/32, 256x256 lower-tri tiles, packed ----------------
__global__ __launch_bounds__(512, 2) void s_gemm256(const unsigned short* __restrict__ Q,
                                                    const unsigned short* __restrict__ K,
                                                    unsigned short* __restrict__ Sp) {
  GEMM_PRE();
  const int bid = blockIdx.x;
  const int sw = (bid & 7) * 68 + (bid >> 3);   // XCD swizzle (544 = 8*68)
  const int b = sw / 136;
  const int tile = sw % 136;
  int I = (int)((sqrtf(8.0f * tile + 1.0f) - 1.0f) * 0.5f);
  while ((I + 1) * (I + 2) / 2 <= tile) ++I;
  while (I * (I + 1) / 2 > tile) --I;
  const int J = tile - I * (I + 1) / 2;
  const char* A = (const char*)Q + ((size_t)b * S_SZ + (size_t)I * 256) * 2048;
  const char* Bp = (const char*)K + ((size_t)b * S_SZ + (size_t)J * 256) * 2048;
  gemm_mainloop(A, 2048, Bp, 2048, 16, sm, tid, acc);
  EPI_IDX();
  const int L = (I + 1) * 256;
  unsigned short* So = Sp + (size_t)b * S_BATCH + (size_t)(I * (I + 1) / 2) * 65536;
#pragma unroll
  for (int f = 0; f < 8; ++f)
#pragma unroll
    for (int g = 0; g < 4; ++g)
#pragma unroll
      for (int j = 0; j < 4; ++j) {
        const int m = wm * 128 + f * 16 + hi * 4 + j;        // local row
        const int n = J * 256 + wn * 64 + g * 16 + lr;       // global col
        float val = acc[f][g][j] * 0.03125f;                 // 1/sqrt(1024)
        if (n > I * 256 + m) val = -1e30f;                   // causal mask
        So[(size_t)m * L + n] = f2bf(val);
      }
}

// ---------------- row softmax in place on packed S (wave per row) ----------------
__global__ __launch_bounds__(256) void softmax_kernel(unsigned short* __restrict__ Sp) {
  const int w = threadIdx.x >> 6, lane = threadIdx.x & 63;
  const int rowflat = blockIdx.x * 4 + w;
  const int rr = 16383 - rowflat;              // heavy rows first
  const int b = rr >> 12, q = rr & 4095;
  const int I = q >> 8;
  const int L = (I + 1) << 8;
  unsigned short* base = Sp + (size_t)b * S_BATCH + (size_t)(I * (I + 1) / 2) * 65536 +
                         (size_t)(q & 255) * L;
  const int niter = (L + 511) >> 9;            // chunks of 512 elems (64 lanes x 8)
  const __bf16 NEG = (__bf16)(-1e30f);
  bf16x8 v[8];
#pragma unroll
  for (int jt = 0; jt < 8; ++jt) {
    if (jt < niter) {
      const int off = jt * 512 + lane * 8;
      if (off < L) v[jt] = *(const bf16x8*)(base + off);
      else { bf16x8 fz; fz[0]=NEG;fz[1]=NEG;fz[2]=NEG;fz[3]=NEG;fz[4]=NEG;fz[5]=NEG;fz[6]=NEG;fz[7]=NEG; v[jt] = fz; }
    }
  }
  float m = -1e30f;
#pragma unroll
  for (int jt = 0; jt < 8; ++jt)
    if (jt < niter)
#pragma unroll
      for (int e = 0; e < 8; ++e) m = fmaxf(m, (float)v[jt][e]);
  m = fmaxf(m, __shfl_xor(m, 1));  m = fmaxf(m, __shfl_xor(m, 2));
  m = fmaxf(m, __shfl_xor(m, 4));  m = fmaxf(m, __shfl_xor(m, 8));
  m = fmaxf(m, __shfl_xor(m, 16)); m = fmaxf(m, __shfl_xor(m, 32));
  float l = 0.f;
#pragma unroll
  for (int jt = 0; jt < 8; ++jt)
    if (jt < niter)
#pragma unroll
      for (int e = 0; e < 8; ++e) l += __expf((float)v[jt][e] - m);
  l += __shfl_xor(l, 1);  l += __shfl_xor(l, 2);  l += __shfl_xor(l, 4);
  l += __shfl_xor(l, 8);  l += __shfl_xor(l, 16); l += __shfl_xor(l, 32);
  const float rl = 1.0f / l;
#pragma unroll
  for (int jt = 0; jt < 8; ++jt) {
    if (jt < niter) {
      const int off = jt * 512 + lane * 8;
      if (off < L) {
        bf16x8 p;
#pragma unroll
        for (int e = 0; e < 8; ++e) p[e] = (__bf16)(__expf((float)v[jt][e] - m) * rl);
        *(bf16x8*)(base + off) = p;
      }
    }
  }
}

// ---------------- O = P V (A = packed P row-block, B^T = Vt), 256 blocks ----------------
__global__ __launch_bounds__(512, 2) void pv256(const unsigned short* __restrict__ Sp,
                                                const unsigned short* __restrict__ Vt,
                                                float* __restrict__ out) {
  GEMM_PRE();
  const int bid = blockIdx.x;
  const int sw = (bid & 7) * 32 + (bid >> 3);   // XCD swizzle (256 = 8*32)
  const int I = sw >> 4, b = (sw >> 2) & 3, nt = sw & 3;
  const int L = (I + 1) * 256;
  const char* A = (const char*)(Sp + (size_t)b * S_BATCH + (size_t)(I * (I + 1) / 2) * 65536);
  const char* Bp = (const char*)Vt + ((size_t)b * D_SZ + (size_t)nt * 256) * (S_SZ * 2);
  gemm_mainloop(A, (size_t)L * 2, Bp, S_SZ * 2, (I + 1) * 4, sm, tid, acc);
  EPI_IDX();
#pragma unroll
  for (int f = 0; f < 8; ++f)
#pragma unroll
    for (int g = 0; g < 4; ++g)
#pragma unroll
      for (int j = 0; j < 4; ++j) {
        const int m = wm * 128 + f * 16 + hi * 4 + j;
        const int n = nt * 256 + wn * 64 + g * 16 + lr;
        out[((size_t)b * S_SZ + (size_t)I * 256 + m) * D_SZ + n] = acc[f][g][j];
      }
}

extern "C" void kernel_launch(void* const* d_in, const int* in_sizes, int n_in,
                              void* d_out, int out_size, void* d_ws, size_t ws_size,
                              hipStream_t stream) {
  (void)in_sizes; (void)n_in; (void)out_size; (void)ws_size;
  const float* x  = (const float*)d_in[0];
  const float* Wq = (const float*)d_in[1];
  const float* Wk = (const float*)d_in[2];
  const float* Wv = (const float*)d_in[3];
  float* out = (float*)d_out;
  unsigned short* ws = (unsigned short*)d_ws;

  cast_x_kernel<<<8192, 256, 0, stream>>>(x, ws + OFF_XB);
  cast_wt_kernel<<<dim3(16, 16, 3), 256, 0, stream>>>(Wq, Wk, Wv, ws + OFF_WT);
  gemm_qkv256<<<768, 512, 0, stream>>>(ws + OFF_XB, ws + OFF_WT,
                                       ws + OFF_Q, ws + OFF_K, ws + OFF_V);
  transpose_v_kernel<<<dim3(64, 16, 4), 256, 0, stream>>>(ws + OFF_V, ws + OFF_VT);
  s_gemm256<<<544, 512, 0, stream>>>(ws + OFF_Q, ws + OFF_K, ws + OFF_S);
  softmax_kernel<<<4096, 256, 0, stream>>>(ws + OFF_S);
  pv256<<<256, 512, 0, stream>>>(ws + OFF_S, ws + OFF_VT, out);
}